// Round 3
// baseline (635.635 us; speedup 1.0000x reference)
//
#include <hip/hip_runtime.h>
#include <hip/hip_bf16.h>
#include <stdint.h>

#define T_TOK 4096
#define H_DIM 2048
#define I_DIM 1024
#define E_NUM 8

using bf16x8  = __attribute__((ext_vector_type(8))) __bf16;
using f32x4   = __attribute__((ext_vector_type(4))) float;
using ushort8 = __attribute__((ext_vector_type(8))) unsigned short;

// RTNE float->bf16 (bit trick; inputs are well within range, NaN not expected)
__device__ __forceinline__ unsigned short f2bf(float f) {
  unsigned int u = __float_as_uint(f);
  u += 0x7fffu + ((u >> 16) & 1u);
  return (unsigned short)(u >> 16);
}

// ---------------- router: logits -> softmax -> top2, fused x->bf16 cast ----------------
__global__ void k_router(const float* __restrict__ x, const float* __restrict__ rw,
                         float* __restrict__ gates, int* __restrict__ idxs,
                         unsigned int* __restrict__ counts, unsigned short* __restrict__ xb) {
  int t = blockIdx.x;
  int lane = threadIdx.x;  // 64 threads = 1 wave
  float acc[E_NUM];
#pragma unroll
  for (int e = 0; e < E_NUM; e++) acc[e] = 0.f;
  const float* xrow = x + (size_t)t * H_DIM;
  for (int h = lane; h < H_DIM; h += 64) {
    float xv = xrow[h];
    xb[(size_t)t * H_DIM + h] = f2bf(xv);
#pragma unroll
    for (int e = 0; e < E_NUM; e++) acc[e] += xv * rw[e * H_DIM + h];
  }
#pragma unroll
  for (int e = 0; e < E_NUM; e++) {
#pragma unroll
    for (int off = 32; off >= 1; off >>= 1) acc[e] += __shfl_xor(acc[e], off, 64);
  }
  if (lane == 0) {
    float mx = acc[0];
#pragma unroll
    for (int e = 1; e < E_NUM; e++) mx = fmaxf(mx, acc[e]);
    float p[E_NUM], s = 0.f;
#pragma unroll
    for (int e = 0; e < E_NUM; e++) { p[e] = __expf(acc[e] - mx); s += p[e]; }
    float inv = 1.f / s;
#pragma unroll
    for (int e = 0; e < E_NUM; e++) p[e] *= inv;
    int i1 = 0, i2 = 0; float m1 = -1.f, m2 = -1.f;
#pragma unroll
    for (int e = 0; e < E_NUM; e++) {
      float v = p[e];
      if (v > m1)      { m2 = m1; i2 = i1; m1 = v; i1 = e; }
      else if (v > m2) { m2 = v; i2 = e; }
    }
    gates[t * 2 + 0] = m1; gates[t * 2 + 1] = m2;
    idxs[t * 2 + 0] = i1;  idxs[t * 2 + 1] = i2;
    atomicAdd(&counts[i1], 1u);
    atomicAdd(&counts[i2], 1u);
  }
}

// ---------------- prefix offsets over 8 experts ----------------
__global__ void k_offsets(const unsigned int* __restrict__ counts,
                          unsigned int* __restrict__ off, unsigned int* __restrict__ cursor) {
  if (threadIdx.x == 0 && blockIdx.x == 0) {
    unsigned int o = 0;
    for (int e = 0; e < E_NUM; e++) { off[e] = o; cursor[e] = o; o += counts[e]; }
  }
}

// ---------------- scatter tokens into per-expert compact lists ----------------
__global__ void k_scatter(const float* __restrict__ gates, const int* __restrict__ idxs,
                          unsigned int* __restrict__ cursor,
                          int* __restrict__ rowlist, float* __restrict__ rowgate) {
  int t = blockIdx.x * blockDim.x + threadIdx.x;
  if (t >= T_TOK) return;
#pragma unroll
  for (int k = 0; k < 2; k++) {
    int e = idxs[t * 2 + k];
    unsigned int pos = atomicAdd(&cursor[e], 1u);
    rowlist[pos] = t;
    rowgate[pos] = gates[t * 2 + k];
  }
}

// ---------------- GEMM1: h[row][i] = silu(x@w1_even) * (x@w1_odd)  ----------------
// block tile: 128 rows x 64 i-cols (= 128 f rows of w1), BK=32, 4 waves (2x2)
__launch_bounds__(256, 2)
__global__ void k_gemm1(const unsigned short* __restrict__ xb, const float* __restrict__ w1,
                        const unsigned int* __restrict__ off, const unsigned int* __restrict__ counts,
                        const int* __restrict__ rowlist, unsigned short* __restrict__ hc) {
  int e = blockIdx.z;
  unsigned int cnt = counts[e];
  unsigned int rb = blockIdx.y;
  if (rb * 128u >= cnt) return;
  unsigned int o = off[e];
  int i0 = blockIdx.x * 64;

  __shared__ unsigned short a_lds[128 * 40];
  __shared__ unsigned short bg_lds[64 * 40];
  __shared__ unsigned short bu_lds[64 * 40];

  int tid = threadIdx.x;
  int lane = tid & 63;
  int wave = tid >> 6;
  int wr = wave >> 1;  // row half (64 rows)
  int wc = wave & 1;   // i half (32 cols)

  const float* w1e = w1 + (size_t)e * (2 * I_DIM) * H_DIM;

  f32x4 accg[4][2], accu[4][2];
#pragma unroll
  for (int m = 0; m < 4; m++)
#pragma unroll
    for (int n = 0; n < 2; n++) {
      accg[m][n] = f32x4{0.f, 0.f, 0.f, 0.f};
      accu[m][n] = f32x4{0.f, 0.f, 0.f, 0.f};
    }

  // gather sources for the 2 A-chunks this thread stages each K-step
  const unsigned short* asrc[2];
#pragma unroll
  for (int it = 0; it < 2; it++) {
    int flat = it * 256 + tid;
    int row = flat >> 2;
    unsigned int pos = rb * 128u + (unsigned int)row;
    unsigned int gp = o + (pos < cnt ? pos : cnt - 1u);
    int tok = rowlist[gp];
    asrc[it] = xb + (size_t)tok * H_DIM;
  }

  for (int k0 = 0; k0 < H_DIM; k0 += 32) {
    __syncthreads();
    // stage A (bf16 rows of x, gathered)
#pragma unroll
    for (int it = 0; it < 2; it++) {
      int flat = it * 256 + tid;
      int row = flat >> 2, q = flat & 3;
      ushort8 v = *reinterpret_cast<const ushort8*>(asrc[it] + k0 + q * 8);
      *reinterpret_cast<ushort8*>(&a_lds[row * 40 + q * 8]) = v;
    }
    // stage W1 rows (fp32 -> bf16), de-interleave even f -> g tile, odd f -> u tile
#pragma unroll
    for (int it = 0; it < 2; it++) {
      int flat = it * 256 + tid;
      int fl = flat >> 2, q = flat & 3;
      const float* src = w1e + (size_t)(2 * i0 + fl) * H_DIM + k0 + q * 8;
      float4 v0 = *reinterpret_cast<const float4*>(src);
      float4 v1 = *reinterpret_cast<const float4*>(src + 4);
      ushort8 b;
      b[0] = f2bf(v0.x); b[1] = f2bf(v0.y); b[2] = f2bf(v0.z); b[3] = f2bf(v0.w);
      b[4] = f2bf(v1.x); b[5] = f2bf(v1.y); b[6] = f2bf(v1.z); b[7] = f2bf(v1.w);
      unsigned short* dst = (fl & 1) ? bu_lds : bg_lds;
      *reinterpret_cast<ushort8*>(&dst[(fl >> 1) * 40 + q * 8]) = b;
    }
    __syncthreads();

    bf16x8 af[4], bgf[2], buf_[2];
#pragma unroll
    for (int m = 0; m < 4; m++) {
      int row = wr * 64 + m * 16 + (lane & 15);
      af[m] = *reinterpret_cast<const bf16x8*>(&a_lds[row * 40 + (lane >> 4) * 8]);
    }
#pragma unroll
    for (int n = 0; n < 2; n++) {
      int c = wc * 32 + n * 16 + (lane & 15);
      bgf[n]  = *reinterpret_cast<const bf16x8*>(&bg_lds[c * 40 + (lane >> 4) * 8]);
      buf_[n] = *reinterpret_cast<const bf16x8*>(&bu_lds[c * 40 + (lane >> 4) * 8]);
    }
#pragma unroll
    for (int m = 0; m < 4; m++)
#pragma unroll
      for (int n = 0; n < 2; n++) {
        accg[m][n] = __builtin_amdgcn_mfma_f32_16x16x32_bf16(af[m], bgf[n],  accg[m][n], 0, 0, 0);
        accu[m][n] = __builtin_amdgcn_mfma_f32_16x16x32_bf16(af[m], buf_[n], accu[m][n], 0, 0, 0);
      }
  }

  // epilogue: h = u * silu(g), store bf16
#pragma unroll
  for (int m = 0; m < 4; m++)
#pragma unroll
    for (int n = 0; n < 2; n++)
#pragma unroll
      for (int r = 0; r < 4; r++) {
        unsigned int grow = rb * 128u + wr * 64 + m * 16 + (lane >> 4) * 4 + r;
        if (grow < cnt) {
          float g = accg[m][n][r], u = accu[m][n][r];
          float h = u * g / (1.f + __expf(-g));
          int ic = i0 + wc * 32 + n * 16 + (lane & 15);
          hc[(size_t)(o + grow) * I_DIM + ic] = f2bf(h);
        }
      }
}

// ---------------- GEMM2: out[tok] += gate * (h @ w2[e]^T) ----------------
// block tile: 128 rows x 128 h-cols, BK=32, 4 waves (2x2), atomic scatter epilogue
__launch_bounds__(256, 2)
__global__ void k_gemm2(const unsigned short* __restrict__ hc, const float* __restrict__ w2,
                        const unsigned int* __restrict__ off, const unsigned int* __restrict__ counts,
                        const int* __restrict__ rowlist, const float* __restrict__ rowgate,
                        float* __restrict__ out) {
  int e = blockIdx.z;
  unsigned int cnt = counts[e];
  unsigned int rb = blockIdx.y;
  if (rb * 128u >= cnt) return;
  unsigned int o = off[e];
  int h0 = blockIdx.x * 128;

  __shared__ unsigned short a_lds[128 * 40];
  __shared__ unsigned short b_lds[128 * 40];

  int tid = threadIdx.x;
  int lane = tid & 63;
  int wave = tid >> 6;
  int wr = wave >> 1;
  int wc = wave & 1;

  const float* w2e = w2 + (size_t)e * H_DIM * I_DIM;

  f32x4 acc[4][4];
#pragma unroll
  for (int m = 0; m < 4; m++)
#pragma unroll
    for (int n = 0; n < 4; n++) acc[m][n] = f32x4{0.f, 0.f, 0.f, 0.f};

  const unsigned short* asrc[2];
#pragma unroll
  for (int it = 0; it < 2; it++) {
    int flat = it * 256 + tid;
    int row = flat >> 2;
    unsigned int pos = rb * 128u + (unsigned int)row;
    unsigned int gp = o + (pos < cnt ? pos : cnt - 1u);
    asrc[it] = hc + (size_t)gp * I_DIM;  // h rows are already expert-contiguous
  }

  for (int k0 = 0; k0 < I_DIM; k0 += 32) {
    __syncthreads();
#pragma unroll
    for (int it = 0; it < 2; it++) {
      int flat = it * 256 + tid;
      int row = flat >> 2, q = flat & 3;
      ushort8 v = *reinterpret_cast<const ushort8*>(asrc[it] + k0 + q * 8);
      *reinterpret_cast<ushort8*>(&a_lds[row * 40 + q * 8]) = v;
    }
#pragma unroll
    for (int it = 0; it < 2; it++) {
      int flat = it * 256 + tid;
      int fl = flat >> 2, q = flat & 3;
      const float* src = w2e + (size_t)(h0 + fl) * I_DIM + k0 + q * 8;
      float4 v0 = *reinterpret_cast<const float4*>(src);
      float4 v1 = *reinterpret_cast<const float4*>(src + 4);
      ushort8 b;
      b[0] = f2bf(v0.x); b[1] = f2bf(v0.y); b[2] = f2bf(v0.z); b[3] = f2bf(v0.w);
      b[4] = f2bf(v1.x); b[5] = f2bf(v1.y); b[6] = f2bf(v1.z); b[7] = f2bf(v1.w);
      *reinterpret_cast<ushort8*>(&b_lds[fl * 40 + q * 8]) = b;
    }
    __syncthreads();

    bf16x8 af[4], bf[4];
#pragma unroll
    for (int m = 0; m < 4; m++) {
      int row = wr * 64 + m * 16 + (lane & 15);
      af[m] = *reinterpret_cast<const bf16x8*>(&a_lds[row * 40 + (lane >> 4) * 8]);
    }
#pragma unroll
    for (int n = 0; n < 4; n++) {
      int c = wc * 64 + n * 16 + (lane & 15);
      bf[n] = *reinterpret_cast<const bf16x8*>(&b_lds[c * 40 + (lane >> 4) * 8]);
    }
#pragma unroll
    for (int m = 0; m < 4; m++)
#pragma unroll
      for (int n = 0; n < 4; n++)
        acc[m][n] = __builtin_amdgcn_mfma_f32_16x16x32_bf16(af[m], bf[n], acc[m][n], 0, 0, 0);
  }

  // epilogue: scatter gate-weighted rows into out with fp32 atomics
#pragma unroll
  for (int m = 0; m < 4; m++)
#pragma unroll
    for (int r = 0; r < 4; r++) {
      unsigned int grow = rb * 128u + wr * 64 + m * 16 + (lane >> 4) * 4 + r;
      if (grow < cnt) {
        int tok = rowlist[o + grow];
        float gate = rowgate[o + grow];
        float* orow = out + (size_t)tok * H_DIM + h0 + wc * 64;
#pragma unroll
        for (int n = 0; n < 4; n++) {
          atomicAdd(&orow[n * 16 + (lane & 15)], gate * acc[m][n][r]);
        }
      }
    }
}

extern "C" void kernel_launch(void* const* d_in, const int* in_sizes, int n_in,
                              void* d_out, int out_size, void* d_ws, size_t ws_size,
                              hipStream_t stream) {
  const float* x  = (const float*)d_in[0];
  const float* rw = (const float*)d_in[1];
  const float* w1 = (const float*)d_in[2];
  const float* w2 = (const float*)d_in[3];
  float* out = (float*)d_out;

  char* ws = (char*)d_ws;
  unsigned int* counts = (unsigned int*)(ws + 0);
  unsigned int* cursor = (unsigned int*)(ws + 64);
  unsigned int* off    = (unsigned int*)(ws + 128);
  float* gates   = (float*)(ws + 4096);
  int*   idxs    = (int*)(ws + 4096 + 32768);
  int*   rowlist = (int*)(ws + 4096 + 65536);
  float* rowgate = (float*)(ws + 4096 + 98304);
  unsigned short* xb = (unsigned short*)(ws + (1u << 20));    // 16 MB
  unsigned short* hc = (unsigned short*)(ws + (18u << 20));   // 16 MB

  hipMemsetAsync(ws, 0, 256, stream);
  hipMemsetAsync(d_out, 0, (size_t)out_size * sizeof(float), stream);

  k_router<<<T_TOK, 64, 0, stream>>>(x, rw, gates, idxs, counts, xb);
  k_offsets<<<1, 64, 0, stream>>>(counts, off, cursor);
  k_scatter<<<T_TOK / 256, 256, 0, stream>>>(gates, idxs, cursor, rowlist, rowgate);
  k_gemm1<<<dim3(I_DIM / 64, T_TOK / 128, E_NUM), 256, 0, stream>>>(xb, w1, off, counts, rowlist, hc);
  k_gemm2<<<dim3(H_DIM / 128, T_TOK / 128, E_NUM), 256, 0, stream>>>(hc, w2, off, counts, rowlist, rowgate, out);
}